// Round 3
// baseline (3400.603 us; speedup 1.0000x reference)
//
#include <hip/hip_runtime.h>

#define NN 50000
#define EE 800000
#define INCH 256
#define D 64
#define ED 16
#define NC 8

// monotone float<->uint key for atomicMax on signed floats
__device__ __forceinline__ unsigned fenc(float f){
  unsigned u = __float_as_uint(f);
  return (u & 0x80000000u) ? ~u : (u | 0x80000000u);
}
__device__ __forceinline__ float fdec(unsigned k){
  unsigned u = (k & 0x80000000u) ? (k ^ 0x80000000u) : ~k;
  return __uint_as_float(u);
}

// fallback scratch if harness ws is too small (~37.2 MB needed)
__device__ __align__(16) char g_ws[40u << 20];

// ---------------- K0: zero-fill workspace (harness-named kernel) ------------
__global__ __launch_bounds__(256) void Adapter_30872224923942_kernel(
    unsigned* __restrict__ ws, int nwords)
{
  int stride = gridDim.x * 256;
  for (int i = blockIdx.x * 256 + threadIdx.x; i < nwords; i += stride)
    ws[i] = 0u;
}

// ---------------- K1: node_feat -> q -> (qk = Wk @ q, qb = q . bk) ----------
// one node per wave; lane = output dim
__global__ __launch_bounds__(256) void k1_node(
    const float* __restrict__ x, const float* __restrict__ Wd, const float* __restrict__ bd,
    const float* __restrict__ Wq, const float* __restrict__ bq,
    const float* __restrict__ Wk, const float* __restrict__ bk,
    float* __restrict__ qk, float* __restrict__ qb)
{
  int lane = threadIdx.x & 63;
  int node = (blockIdx.x << 2) + (threadIdx.x >> 6);
  if (node >= NN) return;
  const float4* xr = (const float4*)(x + (size_t)node * INCH);
  float4 xv = xr[lane];                       // lane holds x[4*lane .. 4*lane+3]
  float nf = bd[lane];
  #pragma unroll
  for (int j = 0; j < 64; ++j){
    float bx = __shfl(xv.x, j), by = __shfl(xv.y, j);
    float bz = __shfl(xv.z, j), bw = __shfl(xv.w, j);
    int c = 4 * j;
    nf = fmaf(bx, Wd[(c  )*D + lane], nf);
    nf = fmaf(by, Wd[(c+1)*D + lane], nf);
    nf = fmaf(bz, Wd[(c+2)*D + lane], nf);
    nf = fmaf(bw, Wd[(c+3)*D + lane], nf);
  }
  nf = fmaxf(nf, 0.0f);
  float qv = bq[lane];
  #pragma unroll
  for (int j = 0; j < D; ++j)
    qv = fmaf(__shfl(nf, j), Wq[j*D + lane], qv);
  float qkv = 0.0f;                           // qk[t] = sum_d Wk[t,d] * q[d]
  #pragma unroll
  for (int t = 0; t < D; ++t)
    qkv = fmaf(__shfl(qv, t), Wk[lane*D + t], qkv);
  float qbv = qv * bk[lane];                  // qb = q . bk
  #pragma unroll
  for (int s = 32; s; s >>= 1) qbv += __shfl_xor(qbv, s);
  qk[(size_t)node*D + lane] = qkv;
  if (lane == 0) qb[node] = qbv;
}

// tf = relu(edge_attr[e] @ Wt + bt) from LDS-staged weights (float4 reads)
__device__ __forceinline__ void compute_tf(
    const float* __restrict__ ea, int e,
    const float4* __restrict__ sWt4, const float4* __restrict__ sbt4, float* tf)
{
  const float4* p = (const float4*)(ea + (size_t)e * ED);
  float4 a0 = p[0], a1 = p[1], a2 = p[2], a3 = p[3];
  float eav[ED] = {a0.x,a0.y,a0.z,a0.w, a1.x,a1.y,a1.z,a1.w,
                   a2.x,a2.y,a2.z,a2.w, a3.x,a3.y,a3.z,a3.w};
  #pragma unroll
  for (int d4 = 0; d4 < D/4; ++d4){
    float4 acc = sbt4[d4];
    #pragma unroll
    for (int j = 0; j < ED; ++j){
      float4 wv = sWt4[j*(D/4) + d4];
      acc.x = fmaf(eav[j], wv.x, acc.x);
      acc.y = fmaf(eav[j], wv.y, acc.y);
      acc.z = fmaf(eav[j], wv.z, acc.z);
      acc.w = fmaf(eav[j], wv.w, acc.w);
    }
    tf[4*d4  ] = fmaxf(acc.x, 0.0f);
    tf[4*d4+1] = fmaxf(acc.y, 0.0f);
    tf[4*d4+2] = fmaxf(acc.z, 0.0f);
    tf[4*d4+3] = fmaxf(acc.w, 0.0f);
  }
}

// ---------------- K2: per-edge tf, cluster argmax, attn; seg-max + counts ---
__global__ __launch_bounds__(256) void k2_edge(
    const float* __restrict__ ea, const int* __restrict__ eidx,
    const float* __restrict__ Wt, const float* __restrict__ bt, const float* __restrict__ ce,
    const float* __restrict__ qk, const float* __restrict__ qb,
    float* __restrict__ attn, int* __restrict__ seg,
    unsigned* __restrict__ m, float* __restrict__ counts, unsigned* __restrict__ epc)
{
  __shared__ float sWt[ED*D];     // 4 KB
  __shared__ float sbt[D];
  __shared__ float sce[NC*D];     // 2 KB
  __shared__ unsigned s_epc[NC];
  int t = threadIdx.x;
  if (t < NC) s_epc[t] = 0u;
  if (t < ED*D/4)  ((float4*)sWt)[t] = ((const float4*)Wt)[t];
  if (t < D/4)     ((float4*)sbt)[t] = ((const float4*)bt)[t];
  if (t < NC*D/4)  ((float4*)sce)[t] = ((const float4*)ce)[t];
  __syncthreads();
  int e = blockIdx.x * 256 + t;
  if (e < EE){
    float tf[D];
    compute_tf(ea, e, (const float4*)sWt, (const float4*)sbt, tf);
    float best = -3.0e38f; int bc = 0;
    const float4* c4 = (const float4*)sce;
    for (int c = 0; c < NC; ++c){
      float s = 0.0f;
      #pragma unroll
      for (int d4 = 0; d4 < D/4; ++d4){
        float4 cv = c4[c*(D/4) + d4];
        s = fmaf(tf[4*d4  ], cv.x, s);
        s = fmaf(tf[4*d4+1], cv.y, s);
        s = fmaf(tf[4*d4+2], cv.z, s);
        s = fmaf(tf[4*d4+3], cv.w, s);
      }
      if (s > best){ best = s; bc = c; }   // strict > == first max (jnp.argmax)
    }
    int src = eidx[e];
    float at = qb[src];
    const float4* qr = (const float4*)(qk + (size_t)src * D);
    #pragma unroll
    for (int v = 0; v < D/4; ++v){
      float4 q4 = qr[v];
      at = fmaf(q4.x, tf[4*v  ], at);
      at = fmaf(q4.y, tf[4*v+1], at);
      at = fmaf(q4.z, tf[4*v+2], at);
      at = fmaf(q4.w, tf[4*v+3], at);
    }
    at *= 0.125f;                      // ADIM^-0.5
    int sg = bc * NN + src;
    attn[e] = at;
    seg[e]  = sg;
    atomicMax(&m[sg], fenc(at));
    atomicAdd(&counts[sg], 1.0f);
    atomicAdd(&s_epc[bc], 1u);
  }
  __syncthreads();
  if (t < NC){
    unsigned v = s_epc[t];
    if (v) atomicAdd(&epc[t], v);
  }
}

// ---------------- K3: denom = segsum(exp(attn - m)); attn <- ex -------------
__global__ __launch_bounds__(256) void k3_denom(
    const int* __restrict__ seg, float* __restrict__ attn,
    const unsigned* __restrict__ m, float* __restrict__ denom)
{
  int e = blockIdx.x * 256 + threadIdx.x;
  if (e >= EE) return;
  int sg = seg[e];
  float ex = __expf(attn[e] - fdec(m[sg]));
  attn[e] = ex;
  atomicAdd(&denom[sg], ex);
}

// ---------------- K4: T[src] += coef*tf, S[src] += coef ---------------------
__global__ __launch_bounds__(256) void k4_scatter(
    const float* __restrict__ ea, const int* __restrict__ eidx,
    const float* __restrict__ Wt, const float* __restrict__ bt,
    const int* __restrict__ seg, const float* __restrict__ attn,
    const float* __restrict__ denom, const float* __restrict__ counts,
    float* __restrict__ T, float* __restrict__ S)
{
  __shared__ float sWt[ED*D];
  __shared__ float sbt[D];
  int t = threadIdx.x;
  if (t < ED*D/4) ((float4*)sWt)[t] = ((const float4*)Wt)[t];
  if (t < D/4)    ((float4*)sbt)[t] = ((const float4*)bt)[t];
  __syncthreads();
  int e = blockIdx.x * 256 + t;
  if (e >= EE) return;
  float tf[D];
  compute_tf(ea, e, (const float4*)sWt, (const float4*)sbt, tf);
  int sg = seg[e];
  float coef = attn[e] / (denom[sg] * fmaxf(counts[sg], 1.0f));  // w_e / cnt
  int src = eidx[e];
  float* Tr = T + (size_t)src * D;
  #pragma unroll
  for (int d = 0; d < D; ++d) atomicAdd(&Tr[d], coef * tf[d]);
  atomicAdd(&S[src], coef);
}

// ---------------- K5: combined -> fused -> out (+residual) ------------------
// combined[n] = (T[n] @ Wv + S[n]*bv) / n_nonempty
__global__ __launch_bounds__(256) void k5_out(
    const float* __restrict__ x, const float* __restrict__ T, const float* __restrict__ S,
    const float* __restrict__ Wv, const float* __restrict__ bv,
    const float* __restrict__ Wo, const float* __restrict__ bo,
    const float* __restrict__ Wu, const float* __restrict__ bu,
    const unsigned* __restrict__ epc, float* __restrict__ out)
{
  int lane = threadIdx.x & 63;
  int node = (blockIdx.x << 2) + (threadIdx.x >> 6);
  if (node >= NN) return;
  float nne = 0.0f;
  #pragma unroll
  for (int c = 0; c < NC; ++c) nne += (epc[c] > 0u) ? 1.0f : 0.0f;
  float inv = 1.0f / fmaxf(nne, 1.0f);
  float Tv = T[(size_t)node*D + lane];
  float Sv = S[node];
  float comb = Sv * bv[lane];
  #pragma unroll
  for (int j = 0; j < D; ++j)
    comb = fmaf(__shfl(Tv, j), Wv[j*D + lane], comb);
  comb *= inv;
  float fu = bo[lane];
  #pragma unroll
  for (int d = 0; d < D; ++d)
    fu = fmaf(__shfl(comb, d), Wo[d*D + lane], fu);
  fu = fmaxf(fu, 0.0f);
  const float4* xr = (const float4*)(x + (size_t)node * INCH);
  float4 xv = xr[lane];
  float4 bu4 = ((const float4*)bu)[lane];
  float4 o;
  o.x = xv.x + bu4.x; o.y = xv.y + bu4.y; o.z = xv.z + bu4.z; o.w = xv.w + bu4.w;
  #pragma unroll
  for (int d = 0; d < D; ++d){
    float f = __shfl(fu, d);
    float4 wv = ((const float4*)(Wu + (size_t)d * INCH))[lane];
    o.x = fmaf(f, wv.x, o.x);
    o.y = fmaf(f, wv.y, o.y);
    o.z = fmaf(f, wv.z, o.z);
    o.w = fmaf(f, wv.w, o.w);
  }
  ((float4*)(out + (size_t)node * INCH))[lane] = o;
}

extern "C" void kernel_launch(void* const* d_in, const int* in_sizes, int n_in,
                              void* d_out, int out_size, void* d_ws, size_t ws_size,
                              hipStream_t stream)
{
  const float* x  = (const float*)d_in[0];
  const float* ea = (const float*)d_in[1];
  const int* eidx = (const int*)d_in[2];      // [2,E]; row 0 = src
  const float* Wd = (const float*)d_in[3];  const float* bd = (const float*)d_in[4];
  const float* Wu = (const float*)d_in[5];  const float* bu = (const float*)d_in[6];
  const float* Wt = (const float*)d_in[7];  const float* bt = (const float*)d_in[8];
  const float* Wq = (const float*)d_in[9];  const float* bq = (const float*)d_in[10];
  const float* Wk = (const float*)d_in[11]; const float* bk = (const float*)d_in[12];
  const float* Wv = (const float*)d_in[13]; const float* bv = (const float*)d_in[14];
  const float* ce = (const float*)d_in[15];
  const float* Wo = (const float*)d_in[16]; const float* bo = (const float*)d_in[17];
  float* out = (float*)d_out;

  size_t need = 0;
  need += (size_t)NN * D * 4;      // T
  need += (size_t)NN * 4;          // S
  need += (size_t)NC * NN * 4;     // m
  need += (size_t)NC * NN * 4;     // denom
  need += (size_t)NC * NN * 4;     // counts
  need += 64;                      // epc
  size_t zbytes = need;
  need += (size_t)NN * D * 4;      // qk
  need += (size_t)NN * 4;          // qb
  need += (size_t)EE * 4;          // attn
  need += (size_t)EE * 4;          // seg

  char* w = (char*)d_ws;
  if (ws_size < need){
    void* p = nullptr;
    hipGetSymbolAddress(&p, HIP_SYMBOL(g_ws));
    w = (char*)p;
  }
  size_t off = 0;
  float*    T      = (float*)(w + off);    off += (size_t)NN * D * 4;
  float*    S      = (float*)(w + off);    off += (size_t)NN * 4;
  unsigned* m      = (unsigned*)(w + off); off += (size_t)NC * NN * 4;
  float*    denom  = (float*)(w + off);    off += (size_t)NC * NN * 4;
  float*    counts = (float*)(w + off);    off += (size_t)NC * NN * 4;
  unsigned* epc    = (unsigned*)(w + off); off += 64;
  float*    qk   = (float*)(w + off);      off += (size_t)NN * D * 4;
  float*    qb   = (float*)(w + off);      off += (size_t)NN * 4;
  float*    attn = (float*)(w + off);      off += (size_t)EE * 4;
  int*      seg  = (int*)(w + off);        off += (size_t)EE * 4;

  int zwords = (int)(zbytes / 4);
  Adapter_30872224923942_kernel<<<dim3(2048), dim3(256), 0, stream>>>((unsigned*)w, zwords);
  k1_node  <<<dim3(NN/4),   dim3(256), 0, stream>>>(x, Wd, bd, Wq, bq, Wk, bk, qk, qb);
  k2_edge  <<<dim3(EE/256), dim3(256), 0, stream>>>(ea, eidx, Wt, bt, ce, qk, qb, attn, seg, m, counts, epc);
  k3_denom <<<dim3(EE/256), dim3(256), 0, stream>>>(seg, attn, m, denom);
  k4_scatter<<<dim3(EE/256),dim3(256), 0, stream>>>(ea, eidx, Wt, bt, seg, attn, denom, counts, T, S);
  k5_out   <<<dim3(NN/4),   dim3(256), 0, stream>>>(x, T, S, Wv, bv, Wo, bo, Wu, bu, epc, out);
}

// Round 4
// 906.279 us; speedup vs baseline: 3.7523x; 3.7523x over previous
//
#include <hip/hip_runtime.h>

#define NN 50000
#define EE 800000
#define INCH 256
#define D 64
#define ED 16
#define NC 8
#define NB 196          // scan blocks: 196*256 = 50176 >= NN
#define NEGINF (-3.0e38f)

// fallback scratch if harness ws is too small (~33 MB needed)
__device__ __align__(16) char g_ws[40u << 20];

// ---------------- K0: zero-fill cnt/fill/epc (harness-named kernel) ---------
__global__ __launch_bounds__(256) void Adapter_30872224923942_kernel(
    unsigned* __restrict__ ws, int nwords)
{
  int stride = gridDim.x * 256;
  for (int i = blockIdx.x * 256 + threadIdx.x; i < nwords; i += stride)
    ws[i] = 0u;
}

// ---------------- P1: histogram of src ------------------------------------
__global__ __launch_bounds__(256) void p1_hist(
    const int* __restrict__ eidx, int* __restrict__ cnt)
{
  int e = blockIdx.x * 256 + threadIdx.x;
  if (e < EE) atomicAdd(&cnt[eidx[e]], 1);
}

// ---------------- S1: per-block exclusive scan ------------------------------
__global__ __launch_bounds__(256) void s1_scan(
    const int* __restrict__ cnt, int* __restrict__ rowptr, int* __restrict__ bsum)
{
  __shared__ int s[256];
  int t = threadIdx.x;
  int i = blockIdx.x * 256 + t;
  int v = (i < NN) ? cnt[i] : 0;
  s[t] = v; __syncthreads();
  #pragma unroll
  for (int off = 1; off < 256; off <<= 1){
    int add = (t >= off) ? s[t - off] : 0;
    __syncthreads();
    s[t] += add;
    __syncthreads();
  }
  if (i < NN) rowptr[i] = s[t] - v;       // exclusive within block
  if (t == 255) bsum[blockIdx.x] = s[255];
}

// ---------------- S2: scan of block sums (1 block) --------------------------
__global__ __launch_bounds__(256) void s2_scan(int* __restrict__ bsum)
{
  __shared__ int s[256];
  int t = threadIdx.x;
  int v = (t < NB) ? bsum[t] : 0;
  s[t] = v; __syncthreads();
  #pragma unroll
  for (int off = 1; off < 256; off <<= 1){
    int add = (t >= off) ? s[t - off] : 0;
    __syncthreads();
    s[t] += add;
    __syncthreads();
  }
  if (t < NB) bsum[t] = s[t] - v;         // exclusive
}

// ---------------- S3: add block offsets ------------------------------------
__global__ __launch_bounds__(256) void s3_add(
    int* __restrict__ rowptr, const int* __restrict__ bsum)
{
  int i = blockIdx.x * 256 + threadIdx.x;
  if (i < NN) rowptr[i] += bsum[blockIdx.x];
  if (i == 0) rowptr[NN] = EE;
}

// ---------------- K1: node_feat -> q -> (qk = Wk @ q, qb = q . bk) ----------
__global__ __launch_bounds__(256) void k1_node(
    const float* __restrict__ x, const float* __restrict__ Wd, const float* __restrict__ bd,
    const float* __restrict__ Wq, const float* __restrict__ bq,
    const float* __restrict__ Wk, const float* __restrict__ bk,
    float* __restrict__ qk, float* __restrict__ qb)
{
  int lane = threadIdx.x & 63;
  int node = (blockIdx.x << 2) + (threadIdx.x >> 6);
  if (node >= NN) return;
  const float4* xr = (const float4*)(x + (size_t)node * INCH);
  float4 xv = xr[lane];
  float nf = bd[lane];
  #pragma unroll
  for (int j = 0; j < 64; ++j){
    float bx = __shfl(xv.x, j), by = __shfl(xv.y, j);
    float bz = __shfl(xv.z, j), bw = __shfl(xv.w, j);
    int c = 4 * j;
    nf = fmaf(bx, Wd[(c  )*D + lane], nf);
    nf = fmaf(by, Wd[(c+1)*D + lane], nf);
    nf = fmaf(bz, Wd[(c+2)*D + lane], nf);
    nf = fmaf(bw, Wd[(c+3)*D + lane], nf);
  }
  nf = fmaxf(nf, 0.0f);
  float qv = bq[lane];
  #pragma unroll
  for (int j = 0; j < D; ++j)
    qv = fmaf(__shfl(nf, j), Wq[j*D + lane], qv);
  float qkv = 0.0f;
  #pragma unroll
  for (int t = 0; t < D; ++t)
    qkv = fmaf(__shfl(qv, t), Wk[lane*D + t], qkv);
  float qbv = qv * bk[lane];
  #pragma unroll
  for (int s = 32; s; s >>= 1) qbv += __shfl_xor(qbv, s);
  qk[(size_t)node*D + lane] = qkv;
  if (lane == 0) qb[node] = qbv;
}

// tf = relu(edge_attr[e] @ Wt + bt) from LDS-staged weights
__device__ __forceinline__ void compute_tf(
    const float* __restrict__ ea, int e,
    const float4* __restrict__ sWt4, const float4* __restrict__ sbt4, float* tf)
{
  const float4* p = (const float4*)(ea + (size_t)e * ED);
  float4 a0 = p[0], a1 = p[1], a2 = p[2], a3 = p[3];
  float eav[ED] = {a0.x,a0.y,a0.z,a0.w, a1.x,a1.y,a1.z,a1.w,
                   a2.x,a2.y,a2.z,a2.w, a3.x,a3.y,a3.z,a3.w};
  #pragma unroll
  for (int d4 = 0; d4 < D/4; ++d4){
    float4 acc = sbt4[d4];
    #pragma unroll
    for (int j = 0; j < ED; ++j){
      float4 wv = sWt4[j*(D/4) + d4];
      acc.x = fmaf(eav[j], wv.x, acc.x);
      acc.y = fmaf(eav[j], wv.y, acc.y);
      acc.z = fmaf(eav[j], wv.z, acc.z);
      acc.w = fmaf(eav[j], wv.w, acc.w);
    }
    tf[4*d4  ] = fmaxf(acc.x, 0.0f);
    tf[4*d4+1] = fmaxf(acc.y, 0.0f);
    tf[4*d4+2] = fmaxf(acc.z, 0.0f);
    tf[4*d4+3] = fmaxf(acc.w, 0.0f);
  }
}

// ---------------- P3: per-edge attn/cluster -> sorted positions -------------
__global__ __launch_bounds__(256) void p3_edge(
    const float* __restrict__ ea, const int* __restrict__ eidx,
    const float* __restrict__ Wt, const float* __restrict__ bt, const float* __restrict__ ce,
    const float* __restrict__ qk, const float* __restrict__ qb,
    const int* __restrict__ rowptr, int* __restrict__ fill,
    float* __restrict__ attnS, int* __restrict__ packS, unsigned* __restrict__ epc)
{
  __shared__ float sWt[ED*D];
  __shared__ float sbt[D];
  __shared__ float sce[NC*D];
  __shared__ unsigned s_epc[NC];
  int t = threadIdx.x;
  if (t < NC) s_epc[t] = 0u;
  if (t < ED*D/4)  ((float4*)sWt)[t] = ((const float4*)Wt)[t];
  if (t < D/4)     ((float4*)sbt)[t] = ((const float4*)bt)[t];
  if (t < NC*D/4)  ((float4*)sce)[t] = ((const float4*)ce)[t];
  __syncthreads();
  int e = blockIdx.x * 256 + t;
  if (e < EE){
    float tf[D];
    compute_tf(ea, e, (const float4*)sWt, (const float4*)sbt, tf);
    float best = NEGINF; int bc = 0;
    const float4* c4 = (const float4*)sce;
    for (int c = 0; c < NC; ++c){
      float s = 0.0f;
      #pragma unroll
      for (int d4 = 0; d4 < D/4; ++d4){
        float4 cv = c4[c*(D/4) + d4];
        s = fmaf(tf[4*d4  ], cv.x, s);
        s = fmaf(tf[4*d4+1], cv.y, s);
        s = fmaf(tf[4*d4+2], cv.z, s);
        s = fmaf(tf[4*d4+3], cv.w, s);
      }
      if (s > best){ best = s; bc = c; }   // strict > == first max (jnp.argmax)
    }
    int src = eidx[e];
    float at = qb[src];
    const float4* qr = (const float4*)(qk + (size_t)src * D);
    #pragma unroll
    for (int v = 0; v < D/4; ++v){
      float4 q4 = qr[v];
      at = fmaf(q4.x, tf[4*v  ], at);
      at = fmaf(q4.y, tf[4*v+1], at);
      at = fmaf(q4.z, tf[4*v+2], at);
      at = fmaf(q4.w, tf[4*v+3], at);
    }
    at *= 0.125f;                       // ADIM^-0.5
    int r = atomicAdd(&fill[src], 1);
    int pos = rowptr[src] + r;
    attnS[pos] = at;
    packS[pos] = e | (bc << 24);
    atomicAdd(&s_epc[bc], 1u);
  }
  __syncthreads();
  if (t < NC){
    unsigned v = s_epc[t];
    if (v) atomicAdd(&epc[t], v);
  }
}

// ---------------- P4: per-node gather (wave per node, no atomics) -----------
__global__ __launch_bounds__(256) void p4_node(
    const float* __restrict__ ea,
    const float* __restrict__ Wt, const float* __restrict__ bt,
    const float* __restrict__ attnS, const int* __restrict__ packS,
    const int* __restrict__ rowptr,
    float* __restrict__ T, float* __restrict__ S)
{
  __shared__ float sWt[ED*D];
  __shared__ float sbt[D];
  int t = threadIdx.x;
  if (t < ED*D/4) ((float4*)sWt)[t] = ((const float4*)Wt)[t];
  if (t < D/4)    ((float4*)sbt)[t] = ((const float4*)bt)[t];
  __syncthreads();
  int lane = t & 63;
  int node = (blockIdx.x << 2) + (t >> 6);
  if (node >= NN) return;
  int start = rowptr[node], end = rowptr[node + 1];

  // pass 1: per-lane per-cluster max + count
  float ml[NC], cl[NC];
  #pragma unroll
  for (int c = 0; c < NC; ++c){ ml[c] = NEGINF; cl[c] = 0.0f; }
  for (int base = start; base < end; base += 64){
    int idx = base + lane;
    bool valid = idx < end;
    float a  = valid ? attnS[idx] : NEGINF;
    int   pc = valid ? (packS[idx] >> 24) : -1;
    #pragma unroll
    for (int c = 0; c < NC; ++c){
      bool hit = (pc == c);
      ml[c] = hit ? fmaxf(ml[c], a) : ml[c];
      cl[c] += hit ? 1.0f : 0.0f;
    }
  }
  #pragma unroll
  for (int c = 0; c < NC; ++c){
    #pragma unroll
    for (int s = 32; s; s >>= 1){
      ml[c] = fmaxf(ml[c], __shfl_xor(ml[c], s));
      cl[c] += __shfl_xor(cl[c], s);
    }
  }
  // pass 2: per-lane per-cluster denom
  float dl[NC];
  #pragma unroll
  for (int c = 0; c < NC; ++c) dl[c] = 0.0f;
  for (int base = start; base < end; base += 64){
    int idx = base + lane;
    bool valid = idx < end;
    float a  = valid ? attnS[idx] : 0.0f;
    int   pc = valid ? (packS[idx] >> 24) : -1;
    float mm = ml[0];
    #pragma unroll
    for (int c = 1; c < NC; ++c) mm = (pc == c) ? ml[c] : mm;
    float ex = valid ? __expf(a - mm) : 0.0f;
    #pragma unroll
    for (int c = 0; c < NC; ++c) dl[c] += (pc == c) ? ex : 0.0f;
  }
  #pragma unroll
  for (int c = 0; c < NC; ++c){
    #pragma unroll
    for (int s = 32; s; s >>= 1) dl[c] += __shfl_xor(dl[c], s);
  }
  // per-cluster coefficient scale: 1/(den*max(cnt,1))
  float rc[NC];
  #pragma unroll
  for (int c = 0; c < NC; ++c)
    rc[c] = 1.0f / (dl[c] * fmaxf(cl[c], 1.0f) + ((cl[c] > 0.0f) ? 0.0f : 1.0f));

  // pass 3: accumulate T[node][lane] over this node's edges
  float Tv = 0.0f, Sv = 0.0f;
  for (int idx = start; idx < end; ++idx){
    float a  = attnS[idx];              // wave-uniform loads
    int   pk = packS[idx];
    int   e  = pk & 0xFFFFFF;
    int   pc = pk >> 24;
    float mm = ml[0], rr = rc[0];
    #pragma unroll
    for (int c = 1; c < NC; ++c){
      bool hit = (pc == c);
      mm = hit ? ml[c] : mm;
      rr = hit ? rc[c] : rr;
    }
    float coef = __expf(a - mm) * rr;
    // tf[lane] from ea row (broadcast loads) and LDS weights
    const float4* p = (const float4*)(ea + (size_t)e * ED);
    float4 a0 = p[0], a1 = p[1], a2 = p[2], a3 = p[3];
    float eav[ED] = {a0.x,a0.y,a0.z,a0.w, a1.x,a1.y,a1.z,a1.w,
                     a2.x,a2.y,a2.z,a2.w, a3.x,a3.y,a3.z,a3.w};
    float tfv = sbt[lane];
    #pragma unroll
    for (int j = 0; j < ED; ++j)
      tfv = fmaf(eav[j], sWt[j*D + lane], tfv);
    tfv = fmaxf(tfv, 0.0f);
    Tv = fmaf(coef, tfv, Tv);
    Sv += coef;
  }
  T[(size_t)node*D + lane] = Tv;
  if (lane == 0) S[node] = Sv;
}

// ---------------- K5: combined -> fused -> out (+residual) ------------------
__global__ __launch_bounds__(256) void k5_out(
    const float* __restrict__ x, const float* __restrict__ T, const float* __restrict__ S,
    const float* __restrict__ Wv, const float* __restrict__ bv,
    const float* __restrict__ Wo, const float* __restrict__ bo,
    const float* __restrict__ Wu, const float* __restrict__ bu,
    const unsigned* __restrict__ epc, float* __restrict__ out)
{
  int lane = threadIdx.x & 63;
  int node = (blockIdx.x << 2) + (threadIdx.x >> 6);
  if (node >= NN) return;
  float nne = 0.0f;
  #pragma unroll
  for (int c = 0; c < NC; ++c) nne += (epc[c] > 0u) ? 1.0f : 0.0f;
  float inv = 1.0f / fmaxf(nne, 1.0f);
  float Tv = T[(size_t)node*D + lane];
  float Sv = S[node];
  float comb = Sv * bv[lane];
  #pragma unroll
  for (int j = 0; j < D; ++j)
    comb = fmaf(__shfl(Tv, j), Wv[j*D + lane], comb);
  comb *= inv;
  float fu = bo[lane];
  #pragma unroll
  for (int d = 0; d < D; ++d)
    fu = fmaf(__shfl(comb, d), Wo[d*D + lane], fu);
  fu = fmaxf(fu, 0.0f);
  const float4* xr = (const float4*)(x + (size_t)node * INCH);
  float4 xv = xr[lane];
  float4 bu4 = ((const float4*)bu)[lane];
  float4 o;
  o.x = xv.x + bu4.x; o.y = xv.y + bu4.y; o.z = xv.z + bu4.z; o.w = xv.w + bu4.w;
  #pragma unroll
  for (int d = 0; d < D; ++d){
    float f = __shfl(fu, d);
    float4 wv = ((const float4*)(Wu + (size_t)d * INCH))[lane];
    o.x = fmaf(f, wv.x, o.x);
    o.y = fmaf(f, wv.y, o.y);
    o.z = fmaf(f, wv.z, o.z);
    o.w = fmaf(f, wv.w, o.w);
  }
  ((float4*)(out + (size_t)node * INCH))[lane] = o;
}

extern "C" void kernel_launch(void* const* d_in, const int* in_sizes, int n_in,
                              void* d_out, int out_size, void* d_ws, size_t ws_size,
                              hipStream_t stream)
{
  const float* x  = (const float*)d_in[0];
  const float* ea = (const float*)d_in[1];
  const int* eidx = (const int*)d_in[2];      // [2,E]; row 0 = src
  const float* Wd = (const float*)d_in[3];  const float* bd = (const float*)d_in[4];
  const float* Wu = (const float*)d_in[5];  const float* bu = (const float*)d_in[6];
  const float* Wt = (const float*)d_in[7];  const float* bt = (const float*)d_in[8];
  const float* Wq = (const float*)d_in[9];  const float* bq = (const float*)d_in[10];
  const float* Wk = (const float*)d_in[11]; const float* bk = (const float*)d_in[12];
  const float* Wv = (const float*)d_in[13]; const float* bv = (const float*)d_in[14];
  const float* ce = (const float*)d_in[15];
  const float* Wo = (const float*)d_in[16]; const float* bo = (const float*)d_in[17];
  float* out = (float*)d_out;

  size_t need = 0;
  need += (size_t)NN * 4;          // cnt
  need += (size_t)NN * 4;          // fill
  need += 64;                      // epc
  size_t zbytes = need;
  need += (size_t)(NN + 4) * 4;    // rowptr
  need += 1024;                    // bsum
  need += (size_t)NN * D * 4;      // qk
  need += (size_t)NN * 4;          // qb
  need += (size_t)EE * 4;          // attnS
  need += (size_t)EE * 4;          // packS
  need += (size_t)NN * D * 4;      // T
  need += (size_t)NN * 4;          // S

  char* w = (char*)d_ws;
  if (ws_size < need){
    void* p = nullptr;
    hipGetSymbolAddress(&p, HIP_SYMBOL(g_ws));
    w = (char*)p;
  }
  size_t off = 0;
  int*      cnt    = (int*)(w + off);      off += (size_t)NN * 4;
  int*      fill   = (int*)(w + off);      off += (size_t)NN * 4;
  unsigned* epc    = (unsigned*)(w + off); off += 64;
  int*      rowptr = (int*)(w + off);      off += (size_t)(NN + 4) * 4;
  int*      bsum   = (int*)(w + off);      off += 1024;
  float*    qk     = (float*)(w + off);    off += (size_t)NN * D * 4;
  float*    qb     = (float*)(w + off);    off += (size_t)NN * 4;
  float*    attnS  = (float*)(w + off);    off += (size_t)EE * 4;
  int*      packS  = (int*)(w + off);      off += (size_t)EE * 4;
  float*    T      = (float*)(w + off);    off += (size_t)NN * D * 4;
  float*    S      = (float*)(w + off);    off += (size_t)NN * 4;

  int zwords = (int)(zbytes / 4);
  Adapter_30872224923942_kernel<<<dim3(512), dim3(256), 0, stream>>>((unsigned*)w, zwords);
  p1_hist<<<dim3((EE+255)/256), dim3(256), 0, stream>>>(eidx, cnt);
  s1_scan<<<dim3(NB),  dim3(256), 0, stream>>>(cnt, rowptr, bsum);
  s2_scan<<<dim3(1),   dim3(256), 0, stream>>>(bsum);
  s3_add <<<dim3(NB),  dim3(256), 0, stream>>>(rowptr, bsum);
  k1_node<<<dim3(NN/4), dim3(256), 0, stream>>>(x, Wd, bd, Wq, bq, Wk, bk, qk, qb);
  p3_edge<<<dim3((EE+255)/256), dim3(256), 0, stream>>>(ea, eidx, Wt, bt, ce, qk, qb,
                                                        rowptr, fill, attnS, packS, epc);
  p4_node<<<dim3((NN+3)/4), dim3(256), 0, stream>>>(ea, Wt, bt, attnS, packS, rowptr, T, S);
  k5_out <<<dim3((NN+3)/4), dim3(256), 0, stream>>>(x, T, S, Wv, bv, Wo, bo, Wu, bu, epc, out);
}

// Round 5
// 530.485 us; speedup vs baseline: 6.4104x; 1.7084x over previous
//
#include <hip/hip_runtime.h>

#define NN 50000
#define EE 800000
#define INCH 256
#define D 64
#define ED 16
#define NC 8
#define NB 196          // scan blocks: 196*256 = 50176 >= NN
#define NEGINF (-3.0e38f)

// fallback scratch (need ~130 MB)
__device__ __align__(16) char g_ws[136u << 20];

__device__ __forceinline__ unsigned short f2b(float f){
  unsigned u = __float_as_uint(f);
  return (unsigned short)((u + 0x7fffu + ((u >> 16) & 1u)) >> 16);
}
__device__ __forceinline__ unsigned packbf(float lo, float hi){
  return (unsigned)f2b(lo) | ((unsigned)f2b(hi) << 16);
}
__device__ __forceinline__ float blo(unsigned w){ return __uint_as_float(w << 16); }
__device__ __forceinline__ float bhi(unsigned w){ return __uint_as_float(w & 0xffff0000u); }

// ---------------- K0: zero cnt/fill/epc (harness-named kernel) --------------
__global__ __launch_bounds__(256) void Adapter_30872224923942_kernel(
    unsigned* __restrict__ ws, int nwords)
{
  int stride = gridDim.x * 256;
  for (int i = blockIdx.x * 256 + threadIdx.x; i < nwords; i += stride)
    ws[i] = 0u;
}

// ---------------- kpre: weight folds + bf16 packs ---------------------------
// M[i][j] = sum_d Wq[i][d]*Wk[j][d]; cvec[j] = sum_d Wk[j][d]*bq[d]
// u[i] = sum_d Wq[i][d]*bk[d]; s0 = bq.bk
// Wvo[i][j] = sum_d Wv[i][d]*Wo[d][j]; bvo[j] = sum_d bv[d]*Wo[d][j]
// WdP[c2*64+j] = pack(Wd[2c2][j], Wd[2c2+1][j])
// WuP[d2*256+c] = pack(Wu[2d2][c], Wu[2d2+1][c])
__global__ __launch_bounds__(256) void kpre(
    const float* __restrict__ Wq, const float* __restrict__ bq,
    const float* __restrict__ Wk, const float* __restrict__ bk,
    const float* __restrict__ Wv, const float* __restrict__ bv,
    const float* __restrict__ Wo, const float* __restrict__ Wd,
    const float* __restrict__ Wu,
    float* __restrict__ M, float* __restrict__ cvec, float* __restrict__ u,
    float* __restrict__ s0, float* __restrict__ Wvo, float* __restrict__ bvo,
    unsigned* __restrict__ WdP, unsigned* __restrict__ WuP)
{
  int b = blockIdx.x, t = threadIdx.x;
  if (b < 16){
    int i = b*4 + (t >> 6), j = t & 63;
    float acc = 0.0f;
    for (int d = 0; d < D; ++d) acc = fmaf(Wq[i*D+d], Wk[j*D+d], acc);
    M[i*D+j] = acc;
  } else if (b < 32){
    int i = (b-16)*4 + (t >> 6), j = t & 63;
    float acc = 0.0f;
    for (int d = 0; d < D; ++d) acc = fmaf(Wv[i*D+d], Wo[d*D+j], acc);
    Wvo[i*D+j] = acc;
  } else if (b < 36){
    for (int k = 0; k < 8; ++k){
      int idx = (b-32)*2048 + t*8 + k;
      int c2 = idx >> 6, j = idx & 63;
      WdP[idx] = packbf(Wd[(2*c2)*D + j], Wd[(2*c2+1)*D + j]);
    }
  } else if (b < 40){
    for (int k = 0; k < 8; ++k){
      int idx = (b-36)*2048 + t*8 + k;
      int d2 = idx >> 8, c = idx & 255;
      WuP[idx] = packbf(Wu[(2*d2)*INCH + c], Wu[(2*d2+1)*INCH + c]);
    }
  } else {
    if (t < 64){
      float acc = 0.0f;
      for (int d = 0; d < D; ++d) acc = fmaf(Wk[t*D+d], bq[d], acc);
      cvec[t] = acc;
    } else if (t < 128){
      int i = t - 64; float acc = 0.0f;
      for (int d = 0; d < D; ++d) acc = fmaf(Wq[i*D+d], bk[d], acc);
      u[i] = acc;
    } else if (t < 192){
      int j = t - 128; float acc = 0.0f;
      for (int d = 0; d < D; ++d) acc = fmaf(bv[d], Wo[d*D+j], acc);
      bvo[j] = acc;
    } else if (t == 192){
      float acc = 0.0f;
      for (int d = 0; d < D; ++d) acc = fmaf(bq[d], bk[d], acc);
      s0[0] = acc;
    }
  }
}

// ---------------- P1: histogram of src --------------------------------------
__global__ __launch_bounds__(256) void p1_hist(
    const int* __restrict__ eidx, int* __restrict__ cnt)
{
  int e = blockIdx.x * 256 + threadIdx.x;
  if (e < EE) atomicAdd(&cnt[eidx[e]], 1);
}

// ---------------- S1..S3: exclusive scan ------------------------------------
__global__ __launch_bounds__(256) void s1_scan(
    const int* __restrict__ cnt, int* __restrict__ rowptr, int* __restrict__ bsum)
{
  __shared__ int s[256];
  int t = threadIdx.x;
  int i = blockIdx.x * 256 + t;
  int v = (i < NN) ? cnt[i] : 0;
  s[t] = v; __syncthreads();
  #pragma unroll
  for (int off = 1; off < 256; off <<= 1){
    int add = (t >= off) ? s[t - off] : 0;
    __syncthreads();
    s[t] += add;
    __syncthreads();
  }
  if (i < NN) rowptr[i] = s[t] - v;
  if (t == 255) bsum[blockIdx.x] = s[255];
}
__global__ __launch_bounds__(256) void s2_scan(int* __restrict__ bsum)
{
  __shared__ int s[256];
  int t = threadIdx.x;
  int v = (t < NB) ? bsum[t] : 0;
  s[t] = v; __syncthreads();
  #pragma unroll
  for (int off = 1; off < 256; off <<= 1){
    int add = (t >= off) ? s[t - off] : 0;
    __syncthreads();
    s[t] += add;
    __syncthreads();
  }
  if (t < NB) bsum[t] = s[t] - v;
}
__global__ __launch_bounds__(256) void s3_add(
    int* __restrict__ rowptr, const int* __restrict__ bsum)
{
  int i = blockIdx.x * 256 + threadIdx.x;
  if (i < NN) rowptr[i] += bsum[blockIdx.x];
  if (i == 0) rowptr[NN] = EE;
}

// ---------------- K1: nf = relu(x@Wd+bd) -> qk = nf@M+cvec, qb = nf.u+s0 ----
// block = 16 nodes, wave = 4 nodes, lane = out dim
__global__ __launch_bounds__(256) void k1_node(
    const float* __restrict__ x, const unsigned* __restrict__ WdP,
    const float* __restrict__ bd, const float* __restrict__ M,
    const float* __restrict__ cvec, const float* __restrict__ u,
    const float* __restrict__ s0p,
    float* __restrict__ qk, float* __restrict__ qb)
{
  __shared__ unsigned sWdP[8192];   // 32 KB
  int t = threadIdx.x;
  #pragma unroll
  for (int i = 0; i < 8; ++i)
    ((uint4*)sWdP)[t + 256*i] = ((const uint4*)WdP)[t + 256*i];
  __syncthreads();
  int lane = t & 63;
  int wg = __builtin_amdgcn_readfirstlane(t >> 6);
  int n0 = blockIdx.x * 16 + wg * 4;
  const float4* xr0 = (const float4*)(x + (size_t)(n0+0) * INCH);
  const float4* xr1 = (const float4*)(x + (size_t)(n0+1) * INCH);
  const float4* xr2 = (const float4*)(x + (size_t)(n0+2) * INCH);
  const float4* xr3 = (const float4*)(x + (size_t)(n0+3) * INCH);
  float bdl = bd[lane];
  float a0 = bdl, a1 = bdl, a2 = bdl, a3 = bdl;
  #pragma unroll 4
  for (int c4 = 0; c4 < 64; ++c4){
    float4 x0 = xr0[c4], x1 = xr1[c4], x2 = xr2[c4], x3 = xr3[c4];
    unsigned wA = sWdP[(c4*2  )*64 + lane];
    unsigned wB = sWdP[(c4*2+1)*64 + lane];
    float w0 = blo(wA), w1 = bhi(wA), w2 = blo(wB), w3 = bhi(wB);
    a0 = fmaf(x0.x,w0,a0); a0 = fmaf(x0.y,w1,a0); a0 = fmaf(x0.z,w2,a0); a0 = fmaf(x0.w,w3,a0);
    a1 = fmaf(x1.x,w0,a1); a1 = fmaf(x1.y,w1,a1); a1 = fmaf(x1.z,w2,a1); a1 = fmaf(x1.w,w3,a1);
    a2 = fmaf(x2.x,w0,a2); a2 = fmaf(x2.y,w1,a2); a2 = fmaf(x2.z,w2,a2); a2 = fmaf(x2.w,w3,a2);
    a3 = fmaf(x3.x,w0,a3); a3 = fmaf(x3.y,w1,a3); a3 = fmaf(x3.z,w2,a3); a3 = fmaf(x3.w,w3,a3);
  }
  float n0f = fmaxf(a0, 0.0f), n1f = fmaxf(a1, 0.0f);
  float n2f = fmaxf(a2, 0.0f), n3f = fmaxf(a3, 0.0f);
  float cvl = cvec[lane];
  float q0 = cvl, q1 = cvl, q2 = cvl, q3 = cvl;
  #pragma unroll 8
  for (int i = 0; i < 64; ++i){
    float mv = M[i*64 + lane];         // L1-resident (16 KB)
    q0 = fmaf(__shfl(n0f, i), mv, q0);
    q1 = fmaf(__shfl(n1f, i), mv, q1);
    q2 = fmaf(__shfl(n2f, i), mv, q2);
    q3 = fmaf(__shfl(n3f, i), mv, q3);
  }
  qk[(size_t)(n0+0)*D + lane] = q0;
  qk[(size_t)(n0+1)*D + lane] = q1;
  qk[(size_t)(n0+2)*D + lane] = q2;
  qk[(size_t)(n0+3)*D + lane] = q3;
  float ul = u[lane], s00 = s0p[0];
  float b0 = n0f*ul, b1 = n1f*ul, b2 = n2f*ul, b3 = n3f*ul;
  #pragma unroll
  for (int s = 32; s; s >>= 1){
    b0 += __shfl_xor(b0, s); b1 += __shfl_xor(b1, s);
    b2 += __shfl_xor(b2, s); b3 += __shfl_xor(b3, s);
  }
  if (lane == 0){
    qb[n0+0] = b0 + s00; qb[n0+1] = b1 + s00;
    qb[n0+2] = b2 + s00; qb[n0+3] = b3 + s00;
  }
}

// ---------------- P3: per-edge tf, cluster, attn -> sorted CSR slots --------
__global__ __launch_bounds__(256) void p3_edge(
    const float* __restrict__ ea, const int* __restrict__ eidx,
    const float* __restrict__ Wt, const float* __restrict__ bt, const float* __restrict__ ce,
    const float* __restrict__ qk, const float* __restrict__ qb,
    const int* __restrict__ rowptr, int* __restrict__ fill,
    float* __restrict__ attnS, int* __restrict__ clS,
    unsigned short* __restrict__ tfS, unsigned* __restrict__ epc)
{
  __shared__ float sWt[ED*D];
  __shared__ float sbt[D];
  __shared__ float sce[NC*D];
  __shared__ unsigned s_epc[NC];
  int t = threadIdx.x;
  if (t < NC) s_epc[t] = 0u;
  if (t < ED*D/4)  ((float4*)sWt)[t] = ((const float4*)Wt)[t];
  if (t < D/4)     ((float4*)sbt)[t] = ((const float4*)bt)[t];
  if (t < NC*D/4)  ((float4*)sce)[t] = ((const float4*)ce)[t];
  __syncthreads();
  int e = blockIdx.x * 256 + t;
  if (e < EE){
    // tf = relu(ea[e] @ Wt + bt)
    const float4* p = (const float4*)(ea + (size_t)e * ED);
    float4 A0 = p[0], A1 = p[1], A2 = p[2], A3 = p[3];
    float eav[ED] = {A0.x,A0.y,A0.z,A0.w, A1.x,A1.y,A1.z,A1.w,
                     A2.x,A2.y,A2.z,A2.w, A3.x,A3.y,A3.z,A3.w};
    float tf[D];
    const float4* sWt4 = (const float4*)sWt;
    const float4* sbt4 = (const float4*)sbt;
    #pragma unroll
    for (int d4 = 0; d4 < D/4; ++d4){
      float4 acc = sbt4[d4];
      #pragma unroll
      for (int j = 0; j < ED; ++j){
        float4 wv = sWt4[j*(D/4) + d4];
        acc.x = fmaf(eav[j], wv.x, acc.x);
        acc.y = fmaf(eav[j], wv.y, acc.y);
        acc.z = fmaf(eav[j], wv.z, acc.z);
        acc.w = fmaf(eav[j], wv.w, acc.w);
      }
      tf[4*d4  ] = fmaxf(acc.x, 0.0f);
      tf[4*d4+1] = fmaxf(acc.y, 0.0f);
      tf[4*d4+2] = fmaxf(acc.z, 0.0f);
      tf[4*d4+3] = fmaxf(acc.w, 0.0f);
    }
    // cluster argmax
    float best = NEGINF; int bc = 0;
    const float4* c4p = (const float4*)sce;
    for (int c = 0; c < NC; ++c){
      float s = 0.0f;
      #pragma unroll
      for (int d4 = 0; d4 < D/4; ++d4){
        float4 cv = c4p[c*(D/4) + d4];
        s = fmaf(tf[4*d4  ], cv.x, s);
        s = fmaf(tf[4*d4+1], cv.y, s);
        s = fmaf(tf[4*d4+2], cv.z, s);
        s = fmaf(tf[4*d4+3], cv.w, s);
      }
      if (s > best){ best = s; bc = c; }   // strict > == first max (jnp.argmax)
    }
    // attn = (qb + qk . tf) / 8
    int src = eidx[e];
    float at = qb[src];
    const float4* qr = (const float4*)(qk + (size_t)src * D);
    #pragma unroll
    for (int v = 0; v < D/4; ++v){
      float4 q4 = qr[v];
      at = fmaf(q4.x, tf[4*v  ], at);
      at = fmaf(q4.y, tf[4*v+1], at);
      at = fmaf(q4.z, tf[4*v+2], at);
      at = fmaf(q4.w, tf[4*v+3], at);
    }
    at *= 0.125f;
    int r = atomicAdd(&fill[src], 1);
    int pos = rowptr[src] + r;
    attnS[pos] = at;
    clS[pos]   = bc;
    uint4* rowq = (uint4*)(tfS + (size_t)pos * D);
    #pragma unroll
    for (int g = 0; g < 8; ++g){
      uint4 v;
      v.x = packbf(tf[8*g+0], tf[8*g+1]);
      v.y = packbf(tf[8*g+2], tf[8*g+3]);
      v.z = packbf(tf[8*g+4], tf[8*g+5]);
      v.w = packbf(tf[8*g+6], tf[8*g+7]);
      rowq[g] = v;
    }
    atomicAdd(&s_epc[bc], 1u);
  }
  __syncthreads();
  if (t < NC){
    unsigned v = s_epc[t];
    if (v) atomicAdd(&epc[t], v);
  }
}

// ---------------- P4: per-node softmax + T accumulation (wave per node) -----
__global__ __launch_bounds__(256) void p4_node(
    const float* __restrict__ attnS, const int* __restrict__ clS,
    const unsigned short* __restrict__ tfS, const int* __restrict__ rowptr,
    float* __restrict__ T, float* __restrict__ S)
{
  __shared__ float s_den[4][NC];
  __shared__ int   s_cnt[4][NC];
  __shared__ float s_inv[4][NC];
  __shared__ float s_coef[4][64];
  int t = threadIdx.x, lane = t & 63, w = t >> 6;
  if (lane < NC){ s_den[w][lane] = 0.0f; s_cnt[w][lane] = 0; }
  int node = blockIdx.x * 4 + w;
  int start = rowptr[node], end = rowptr[node + 1];
  // pass A1: per-cluster denom + count (no max shift needed: |attn| ~ O(1))
  for (int base = start; base < end; base += 64){
    int idx = base + lane;
    if (idx < end){
      float ex = __expf(attnS[idx]);
      int c = clS[idx];
      atomicAdd(&s_den[w][c], ex);
      atomicAdd(&s_cnt[w][c], 1);
    }
  }
  if (lane < NC){
    int   cc = s_cnt[w][lane];
    float dd = s_den[w][lane];
    s_inv[w][lane] = (cc > 0) ? 1.0f / (dd * (float)cc) : 0.0f;
    float sv = (cc > 0) ? 1.0f / (float)cc : 0.0f;  // sum of coefs closed-form
    sv += __shfl_xor(sv, 1); sv += __shfl_xor(sv, 2); sv += __shfl_xor(sv, 4);
    if (lane == 0) S[node] = sv;
  }
  // pass A2+B: coef -> LDS, then sequential gather of bf16 tf rows
  float Tacc = 0.0f;
  for (int base = start; base < end; base += 64){
    int idx = base + lane;
    if (idx < end)
      s_coef[w][lane] = __expf(attnS[idx]) * s_inv[w][clS[idx]];
    int mm = min(64, end - base);
    for (int tt = 0; tt < mm; ++tt){
      float coef = s_coef[w][tt];      // uniform broadcast
      float tfv = __uint_as_float(((unsigned)tfS[(size_t)(base + tt) * D + lane]) << 16);
      Tacc = fmaf(coef, tfv, Tacc);
    }
  }
  T[(size_t)node * D + lane] = Tacc;
}

// ---------------- K5: fu = relu((T@Wvo + S*bvo)/nne + bo); out = x + fu@Wu+bu
__global__ __launch_bounds__(256) void k5_out(
    const float* __restrict__ x, const float* __restrict__ T, const float* __restrict__ S,
    const float* __restrict__ Wvo, const float* __restrict__ bvo,
    const unsigned* __restrict__ WuP, const float* __restrict__ bu,
    const float* __restrict__ bo, const unsigned* __restrict__ epc,
    float* __restrict__ out)
{
  __shared__ unsigned sWuP[8192];   // 32 KB packed bf16 Wu
  __shared__ float s_fu[16*64];     // 4 KB
  int t = threadIdx.x;
  #pragma unroll
  for (int i = 0; i < 8; ++i)
    ((uint4*)sWuP)[t + 256*i] = ((const uint4*)WuP)[t + 256*i];
  int lane = t & 63;
  int wg = __builtin_amdgcn_readfirstlane(t >> 6);
  int n0 = blockIdx.x * 16 + wg * 4;
  float nne = 0.0f;
  #pragma unroll
  for (int c = 0; c < NC; ++c) nne += (epc[c] > 0u) ? 1.0f : 0.0f;
  float inv = 1.0f / fmaxf(nne, 1.0f);
  float T0 = T[(size_t)(n0+0)*D + lane];
  float T1 = T[(size_t)(n0+1)*D + lane];
  float T2 = T[(size_t)(n0+2)*D + lane];
  float T3 = T[(size_t)(n0+3)*D + lane];
  float bvl = bvo[lane], bol = bo[lane];
  float f0 = S[n0+0]*bvl, f1 = S[n0+1]*bvl, f2 = S[n0+2]*bvl, f3 = S[n0+3]*bvl;
  #pragma unroll 8
  for (int i = 0; i < 64; ++i){
    float wv = Wvo[i*64 + lane];      // L1-resident (16 KB)
    f0 = fmaf(__shfl(T0, i), wv, f0);
    f1 = fmaf(__shfl(T1, i), wv, f1);
    f2 = fmaf(__shfl(T2, i), wv, f2);
    f3 = fmaf(__shfl(T3, i), wv, f3);
  }
  f0 = fmaxf(f0*inv + bol, 0.0f);
  f1 = fmaxf(f1*inv + bol, 0.0f);
  f2 = fmaxf(f2*inv + bol, 0.0f);
  f3 = fmaxf(f3*inv + bol, 0.0f);
  s_fu[(wg*4+0)*64 + lane] = f0;
  s_fu[(wg*4+1)*64 + lane] = f1;
  s_fu[(wg*4+2)*64 + lane] = f2;
  s_fu[(wg*4+3)*64 + lane] = f3;
  __syncthreads();                    // sWuP staging complete (and fu visible)
  float4 bu4 = ((const float4*)bu)[lane];
  float4 o0 = ((const float4*)(x + (size_t)(n0+0)*INCH))[lane];
  float4 o1 = ((const float4*)(x + (size_t)(n0+1)*INCH))[lane];
  float4 o2 = ((const float4*)(x + (size_t)(n0+2)*INCH))[lane];
  float4 o3 = ((const float4*)(x + (size_t)(n0+3)*INCH))[lane];
  o0.x += bu4.x; o0.y += bu4.y; o0.z += bu4.z; o0.w += bu4.w;
  o1.x += bu4.x; o1.y += bu4.y; o1.z += bu4.z; o1.w += bu4.w;
  o2.x += bu4.x; o2.y += bu4.y; o2.z += bu4.z; o2.w += bu4.w;
  o3.x += bu4.x; o3.y += bu4.y; o3.z += bu4.z; o3.w += bu4.w;
  const float2* fu2 = (const float2*)s_fu;
  #pragma unroll 4
  for (int d2 = 0; d2 < 32; ++d2){
    uint4 wp = *(const uint4*)&sWuP[d2*256 + lane*4];
    float4 wl = { blo(wp.x), blo(wp.y), blo(wp.z), blo(wp.w) };
    float4 wh = { bhi(wp.x), bhi(wp.y), bhi(wp.z), bhi(wp.w) };
    float2 g0 = fu2[(wg*4+0)*32 + d2];
    float2 g1 = fu2[(wg*4+1)*32 + d2];
    float2 g2 = fu2[(wg*4+2)*32 + d2];
    float2 g3 = fu2[(wg*4+3)*32 + d2];
    o0.x = fmaf(g0.x, wl.x, o0.x); o0.y = fmaf(g0.x, wl.y, o0.y);
    o0.z = fmaf(g0.x, wl.z, o0.z); o0.w = fmaf(g0.x, wl.w, o0.w);
    o0.x = fmaf(g0.y, wh.x, o0.x); o0.y = fmaf(g0.y, wh.y, o0.y);
    o0.z = fmaf(g0.y, wh.z, o0.z); o0.w = fmaf(g0.y, wh.w, o0.w);
    o1.x = fmaf(g1.x, wl.x, o1.x); o1.y = fmaf(g1.x, wl.y, o1.y);
    o1.z = fmaf(g1.x, wl.z, o1.z); o1.w = fmaf(g1.x, wl.w, o1.w);
    o1.x = fmaf(g1.y, wh.x, o1.x); o1.y = fmaf(g1.y, wh.y, o1.y);
    o1.z = fmaf(g1.y, wh.z, o1.z); o1.w = fmaf(g1.y, wh.w, o1.w);
    o2.x = fmaf(g2.x, wl.x, o2.x); o2.y = fmaf(g2.x, wl.y, o2.y);
    o2.z = fmaf(g2.x, wl.z, o2.z); o2.w = fmaf(g2.x, wl.w, o2.w);
    o2.x = fmaf(g2.y, wh.x, o2.x); o2.y = fmaf(g2.y, wh.y, o2.y);
    o2.z = fmaf(g2.y, wh.z, o2.z); o2.w = fmaf(g2.y, wh.w, o2.w);
    o3.x = fmaf(g3.x, wl.x, o3.x); o3.y = fmaf(g3.x, wl.y, o3.y);
    o3.z = fmaf(g3.x, wl.z, o3.z); o3.w = fmaf(g3.x, wl.w, o3.w);
    o3.x = fmaf(g3.y, wh.x, o3.x); o3.y = fmaf(g3.y, wh.y, o3.y);
    o3.z = fmaf(g3.y, wh.z, o3.z); o3.w = fmaf(g3.y, wh.w, o3.w);
  }
  ((float4*)(out + (size_t)(n0+0)*INCH))[lane] = o0;
  ((float4*)(out + (size_t)(n0+1)*INCH))[lane] = o1;
  ((float4*)(out + (size_t)(n0+2)*INCH))[lane] = o2;
  ((float4*)(out + (size_t)(n0+3)*INCH))[lane] = o3;
}

extern "C" void kernel_launch(void* const* d_in, const int* in_sizes, int n_in,
                              void* d_out, int out_size, void* d_ws, size_t ws_size,
                              hipStream_t stream)
{
  const float* x  = (const float*)d_in[0];
  const float* ea = (const float*)d_in[1];
  const int* eidx = (const int*)d_in[2];      // [2,E]; row 0 = src
  const float* Wd = (const float*)d_in[3];  const float* bd = (const float*)d_in[4];
  const float* Wu = (const float*)d_in[5];  const float* bu = (const float*)d_in[6];
  const float* Wt = (const float*)d_in[7];  const float* bt = (const float*)d_in[8];
  const float* Wq = (const float*)d_in[9];  const float* bq = (const float*)d_in[10];
  const float* Wk = (const float*)d_in[11]; const float* bk = (const float*)d_in[12];
  const float* Wv = (const float*)d_in[13]; const float* bv = (const float*)d_in[14];
  const float* ce = (const float*)d_in[15];
  const float* Wo = (const float*)d_in[16]; const float* bo = (const float*)d_in[17];
  float* out = (float*)d_out;

  size_t need = 0;
  need += (size_t)NN*4;          // cnt
  need += (size_t)NN*4;          // fill
  need += 64;                    // epc
  size_t zbytes = need;          // zero region
  need += (size_t)(NN+4)*4;      // rowptr
  need += 1024;                  // bsum
  need += (size_t)NN*D*4;        // qk
  need += (size_t)NN*4;          // qb
  need += (size_t)EE*4;          // attnS
  need += (size_t)EE*4;          // clS
  need += (size_t)EE*D*2;        // tfS (bf16)
  need += (size_t)NN*D*4;        // T
  need += (size_t)NN*4;          // S
  need += 4096*4 + 256 + 256 + 16 + 4096*4 + 256;  // M,cvec,u,s0,Wvo,bvo
  need += 8192*4 + 8192*4;       // WdP, WuP

  char* w = (char*)d_ws;
  if (ws_size < need){
    void* p = nullptr;
    hipGetSymbolAddress(&p, HIP_SYMBOL(g_ws));
    w = (char*)p;
  }
  size_t off = 0;
  int*      cnt    = (int*)(w + off);      off += (size_t)NN*4;
  int*      fill   = (int*)(w + off);      off += (size_t)NN*4;
  unsigned* epc    = (unsigned*)(w + off); off += 64;
  int*      rowptr = (int*)(w + off);      off += (size_t)(NN+4)*4;
  int*      bsum   = (int*)(w + off);      off += 1024;
  float*    qk     = (float*)(w + off);    off += (size_t)NN*D*4;
  float*    qb     = (float*)(w + off);    off += (size_t)NN*4;
  float*    attnS  = (float*)(w + off);    off += (size_t)EE*4;
  int*      clS    = (int*)(w + off);      off += (size_t)EE*4;
  unsigned short* tfS = (unsigned short*)(w + off); off += (size_t)EE*D*2;
  float*    T      = (float*)(w + off);    off += (size_t)NN*D*4;
  float*    S      = (float*)(w + off);    off += (size_t)NN*4;
  float*    M      = (float*)(w + off);    off += 4096*4;
  float*    cvec   = (float*)(w + off);    off += 256;
  float*    u      = (float*)(w + off);    off += 256;
  float*    s0     = (float*)(w + off);    off += 16;
  float*    Wvo    = (float*)(w + off);    off += 4096*4;
  float*    bvo    = (float*)(w + off);    off += 256;
  unsigned* WdP    = (unsigned*)(w + off); off += 8192*4;
  unsigned* WuP    = (unsigned*)(w + off); off += 8192*4;

  int zwords = (int)(zbytes / 4);
  Adapter_30872224923942_kernel<<<dim3(256), dim3(256), 0, stream>>>((unsigned*)w, zwords);
  kpre<<<dim3(41), dim3(256), 0, stream>>>(Wq, bq, Wk, bk, Wv, bv, Wo, Wd, Wu,
                                           M, cvec, u, s0, Wvo, bvo, WdP, WuP);
  p1_hist<<<dim3(EE/256), dim3(256), 0, stream>>>(eidx, cnt);
  s1_scan<<<dim3(NB), dim3(256), 0, stream>>>(cnt, rowptr, bsum);
  s2_scan<<<dim3(1),  dim3(256), 0, stream>>>(bsum);
  s3_add <<<dim3(NB), dim3(256), 0, stream>>>(rowptr, bsum);
  k1_node<<<dim3(NN/16), dim3(256), 0, stream>>>(x, WdP, bd, M, cvec, u, s0, qk, qb);
  p3_edge<<<dim3(EE/256), dim3(256), 0, stream>>>(ea, eidx, Wt, bt, ce, qk, qb,
                                                  rowptr, fill, attnS, clS, tfS, epc);
  p4_node<<<dim3(NN/4), dim3(256), 0, stream>>>(attnS, clS, tfS, rowptr, T, S);
  k5_out <<<dim3(NN/16), dim3(256), 0, stream>>>(x, T, S, Wvo, bvo, WuP, bu, bo, epc, out);
}

// Round 6
// 477.258 us; speedup vs baseline: 7.1253x; 1.1115x over previous
//
#include <hip/hip_runtime.h>

#define NN 50000
#define EE 800000
#define INCH 256
#define D 64
#define ED 16
#define NC 8
#define NB 196          // scan blocks: 196*256 = 50176 >= NN
#define NEGINF (-3.0e38f)

// fallback scratch (need ~32 MB)
__device__ __align__(16) char g_ws[64u << 20];

__device__ __forceinline__ unsigned short f2b(float f){
  unsigned u = __float_as_uint(f);
  return (unsigned short)((u + 0x7fffu + ((u >> 16) & 1u)) >> 16);
}
__device__ __forceinline__ unsigned packbf(float lo, float hi){
  return (unsigned)f2b(lo) | ((unsigned)f2b(hi) << 16);
}
__device__ __forceinline__ float blo(unsigned w){ return __uint_as_float(w << 16); }
__device__ __forceinline__ float bhi(unsigned w){ return __uint_as_float(w & 0xffff0000u); }

// ---------------- K0: zero cnt/fill/epc (harness-named kernel) --------------
__global__ __launch_bounds__(256) void Adapter_30872224923942_kernel(
    unsigned* __restrict__ ws, int nwords)
{
  int stride = gridDim.x * 256;
  for (int i = blockIdx.x * 256 + threadIdx.x; i < nwords; i += stride)
    ws[i] = 0u;
}

// ---------------- kpre: weight folds + bf16 packs ---------------------------
__global__ __launch_bounds__(256) void kpre(
    const float* __restrict__ Wq, const float* __restrict__ bq,
    const float* __restrict__ Wk, const float* __restrict__ bk,
    const float* __restrict__ Wv, const float* __restrict__ bv,
    const float* __restrict__ Wo, const float* __restrict__ Wd,
    const float* __restrict__ Wu,
    float* __restrict__ M, float* __restrict__ cvec, float* __restrict__ u,
    float* __restrict__ s0, float* __restrict__ Wvo, float* __restrict__ bvo,
    unsigned* __restrict__ WdP, unsigned* __restrict__ WuP)
{
  int b = blockIdx.x, t = threadIdx.x;
  if (b < 16){
    int i = b*4 + (t >> 6), j = t & 63;
    float acc = 0.0f;
    for (int d = 0; d < D; ++d) acc = fmaf(Wq[i*D+d], Wk[j*D+d], acc);
    M[i*D+j] = acc;
  } else if (b < 32){
    int i = (b-16)*4 + (t >> 6), j = t & 63;
    float acc = 0.0f;
    for (int d = 0; d < D; ++d) acc = fmaf(Wv[i*D+d], Wo[d*D+j], acc);
    Wvo[i*D+j] = acc;
  } else if (b < 36){
    for (int k = 0; k < 8; ++k){
      int idx = (b-32)*2048 + t*8 + k;
      int c2 = idx >> 6, j = idx & 63;
      WdP[idx] = packbf(Wd[(2*c2)*D + j], Wd[(2*c2+1)*D + j]);
    }
  } else if (b < 40){
    for (int k = 0; k < 8; ++k){
      int idx = (b-36)*2048 + t*8 + k;
      int d2 = idx >> 8, c = idx & 255;
      WuP[idx] = packbf(Wu[(2*d2)*INCH + c], Wu[(2*d2+1)*INCH + c]);
    }
  } else {
    if (t < 64){
      float acc = 0.0f;
      for (int d = 0; d < D; ++d) acc = fmaf(Wk[t*D+d], bq[d], acc);
      cvec[t] = acc;
    } else if (t < 128){
      int i = t - 64; float acc = 0.0f;
      for (int d = 0; d < D; ++d) acc = fmaf(Wq[i*D+d], bk[d], acc);
      u[i] = acc;
    } else if (t < 192){
      int j = t - 128; float acc = 0.0f;
      for (int d = 0; d < D; ++d) acc = fmaf(bv[d], Wo[d*D+j], acc);
      bvo[j] = acc;
    } else if (t == 192){
      float acc = 0.0f;
      for (int d = 0; d < D; ++d) acc = fmaf(bq[d], bk[d], acc);
      s0[0] = acc;
    }
  }
}

// ---------------- P1: histogram of src --------------------------------------
__global__ __launch_bounds__(256) void p1_hist(
    const int* __restrict__ eidx, int* __restrict__ cnt)
{
  int e = blockIdx.x * 256 + threadIdx.x;
  if (e < EE) atomicAdd(&cnt[eidx[e]], 1);
}

// ---------------- S1..S3: exclusive scan ------------------------------------
__global__ __launch_bounds__(256) void s1_scan(
    const int* __restrict__ cnt, int* __restrict__ rowptr, int* __restrict__ bsum)
{
  __shared__ int s[256];
  int t = threadIdx.x;
  int i = blockIdx.x * 256 + t;
  int v = (i < NN) ? cnt[i] : 0;
  s[t] = v; __syncthreads();
  #pragma unroll
  for (int off = 1; off < 256; off <<= 1){
    int add = (t >= off) ? s[t - off] : 0;
    __syncthreads();
    s[t] += add;
    __syncthreads();
  }
  if (i < NN) rowptr[i] = s[t] - v;
  if (t == 255) bsum[blockIdx.x] = s[255];
}
__global__ __launch_bounds__(256) void s2_scan(int* __restrict__ bsum)
{
  __shared__ int s[256];
  int t = threadIdx.x;
  int v = (t < NB) ? bsum[t] : 0;
  s[t] = v; __syncthreads();
  #pragma unroll
  for (int off = 1; off < 256; off <<= 1){
    int add = (t >= off) ? s[t - off] : 0;
    __syncthreads();
    s[t] += add;
    __syncthreads();
  }
  if (t < NB) bsum[t] = s[t] - v;
}
__global__ __launch_bounds__(256) void s3_add(
    int* __restrict__ rowptr, const int* __restrict__ bsum)
{
  int i = blockIdx.x * 256 + threadIdx.x;
  if (i < NN) rowptr[i] += bsum[blockIdx.x];
  if (i == 0) rowptr[NN] = EE;
}

// ---------------- P2: build CSR pair list (the one amplified scatter) -------
__global__ __launch_bounds__(256) void p2_build(
    const int* __restrict__ eidx, const int* __restrict__ rowptr,
    int* __restrict__ fill, int2* __restrict__ pairS)
{
  int e = blockIdx.x * 256 + threadIdx.x;
  if (e >= EE) return;
  int src = eidx[e];
  int r = atomicAdd(&fill[src], 1);
  int2 pr; pr.x = e; pr.y = src;
  pairS[rowptr[src] + r] = pr;
}

// ---------------- K1: nf = relu(x@Wd+bd) -> qkH = bf16(nf@M+cvec), qb -------
__global__ __launch_bounds__(256) void k1_node(
    const float* __restrict__ x, const unsigned* __restrict__ WdP,
    const float* __restrict__ bd, const float* __restrict__ M,
    const float* __restrict__ cvec, const float* __restrict__ u,
    const float* __restrict__ s0p,
    unsigned short* __restrict__ qkH, float* __restrict__ qb)
{
  __shared__ unsigned sWdP[8192];   // 32 KB
  int t = threadIdx.x;
  #pragma unroll
  for (int i = 0; i < 8; ++i)
    ((uint4*)sWdP)[t + 256*i] = ((const uint4*)WdP)[t + 256*i];
  __syncthreads();
  int lane = t & 63;
  int wg = __builtin_amdgcn_readfirstlane(t >> 6);
  int n0 = blockIdx.x * 16 + wg * 4;
  const float4* xr0 = (const float4*)(x + (size_t)(n0+0) * INCH);
  const float4* xr1 = (const float4*)(x + (size_t)(n0+1) * INCH);
  const float4* xr2 = (const float4*)(x + (size_t)(n0+2) * INCH);
  const float4* xr3 = (const float4*)(x + (size_t)(n0+3) * INCH);
  float bdl = bd[lane];
  float a0 = bdl, a1 = bdl, a2 = bdl, a3 = bdl;
  #pragma unroll 4
  for (int c4 = 0; c4 < 64; ++c4){
    float4 x0 = xr0[c4], x1 = xr1[c4], x2 = xr2[c4], x3 = xr3[c4];
    unsigned wA = sWdP[(c4*2  )*64 + lane];
    unsigned wB = sWdP[(c4*2+1)*64 + lane];
    float w0 = blo(wA), w1 = bhi(wA), w2 = blo(wB), w3 = bhi(wB);
    a0 = fmaf(x0.x,w0,a0); a0 = fmaf(x0.y,w1,a0); a0 = fmaf(x0.z,w2,a0); a0 = fmaf(x0.w,w3,a0);
    a1 = fmaf(x1.x,w0,a1); a1 = fmaf(x1.y,w1,a1); a1 = fmaf(x1.z,w2,a1); a1 = fmaf(x1.w,w3,a1);
    a2 = fmaf(x2.x,w0,a2); a2 = fmaf(x2.y,w1,a2); a2 = fmaf(x2.z,w2,a2); a2 = fmaf(x2.w,w3,a2);
    a3 = fmaf(x3.x,w0,a3); a3 = fmaf(x3.y,w1,a3); a3 = fmaf(x3.z,w2,a3); a3 = fmaf(x3.w,w3,a3);
  }
  float n0f = fmaxf(a0, 0.0f), n1f = fmaxf(a1, 0.0f);
  float n2f = fmaxf(a2, 0.0f), n3f = fmaxf(a3, 0.0f);
  float cvl = cvec[lane];
  float q0 = cvl, q1 = cvl, q2 = cvl, q3 = cvl;
  #pragma unroll 8
  for (int i = 0; i < 64; ++i){
    float mv = M[i*64 + lane];         // L1-resident (16 KB)
    q0 = fmaf(__shfl(n0f, i), mv, q0);
    q1 = fmaf(__shfl(n1f, i), mv, q1);
    q2 = fmaf(__shfl(n2f, i), mv, q2);
    q3 = fmaf(__shfl(n3f, i), mv, q3);
  }
  qkH[(size_t)(n0+0)*D + lane] = f2b(q0);
  qkH[(size_t)(n0+1)*D + lane] = f2b(q1);
  qkH[(size_t)(n0+2)*D + lane] = f2b(q2);
  qkH[(size_t)(n0+3)*D + lane] = f2b(q3);
  float ul = u[lane], s00 = s0p[0];
  float b0 = n0f*ul, b1 = n1f*ul, b2 = n2f*ul, b3 = n3f*ul;
  #pragma unroll
  for (int s = 32; s; s >>= 1){
    b0 += __shfl_xor(b0, s); b1 += __shfl_xor(b1, s);
    b2 += __shfl_xor(b2, s); b3 += __shfl_xor(b3, s);
  }
  if (lane == 0){
    qb[n0+0] = b0 + s00; qb[n0+1] = b1 + s00;
    qb[n0+2] = b2 + s00; qb[n0+3] = b3 + s00;
  }
}

// ---------------- P3: CSR-ordered per-edge tf, cluster, attn ----------------
// pos-order: qk/qb reads are L1 broadcasts; attn/cl writes coalesced.
__global__ __launch_bounds__(256) void p3_edge(
    const float* __restrict__ ea, const int2* __restrict__ pairS,
    const float* __restrict__ Wt, const float* __restrict__ bt, const float* __restrict__ ce,
    const unsigned short* __restrict__ qkH, const float* __restrict__ qb,
    float* __restrict__ attnS, unsigned char* __restrict__ clS,
    unsigned* __restrict__ epc)
{
  __shared__ float sWt[ED*D];     // 4 KB
  __shared__ float sbt[D];
  __shared__ float sce[NC*D];     // 2 KB
  __shared__ unsigned s_epc[NC];
  int t = threadIdx.x;
  if (t < NC) s_epc[t] = 0u;
  if (t < ED*D/4)  ((float4*)sWt)[t] = ((const float4*)Wt)[t];
  if (t < D/4)     ((float4*)sbt)[t] = ((const float4*)bt)[t];
  if (t < NC*D/4)  ((float4*)sce)[t] = ((const float4*)ce)[t];
  __syncthreads();
  int pos = blockIdx.x * 256 + t;
  int2 pr = pairS[pos];
  int e = pr.x, src = pr.y;
  // tf = relu(ea[e] @ Wt + bt)   (ea row = 64 B = 1 line, random gather)
  const float4* p = (const float4*)(ea + (size_t)e * ED);
  float4 A0 = p[0], A1 = p[1], A2 = p[2], A3 = p[3];
  float eav[ED] = {A0.x,A0.y,A0.z,A0.w, A1.x,A1.y,A1.z,A1.w,
                   A2.x,A2.y,A2.z,A2.w, A3.x,A3.y,A3.z,A3.w};
  float tf[D];
  const float4* sWt4 = (const float4*)sWt;
  const float4* sbt4 = (const float4*)sbt;
  #pragma unroll
  for (int d4 = 0; d4 < D/4; ++d4){
    float4 acc = sbt4[d4];
    #pragma unroll
    for (int j = 0; j < ED; ++j){
      float4 wv = sWt4[j*(D/4) + d4];
      acc.x = fmaf(eav[j], wv.x, acc.x);
      acc.y = fmaf(eav[j], wv.y, acc.y);
      acc.z = fmaf(eav[j], wv.z, acc.z);
      acc.w = fmaf(eav[j], wv.w, acc.w);
    }
    tf[4*d4  ] = fmaxf(acc.x, 0.0f);
    tf[4*d4+1] = fmaxf(acc.y, 0.0f);
    tf[4*d4+2] = fmaxf(acc.z, 0.0f);
    tf[4*d4+3] = fmaxf(acc.w, 0.0f);
  }
  // cluster argmax (strict > == first max, jnp.argmax)
  float best = NEGINF; int bc = 0;
  const float4* c4p = (const float4*)sce;
  for (int c = 0; c < NC; ++c){
    float s = 0.0f;
    #pragma unroll
    for (int d4 = 0; d4 < D/4; ++d4){
      float4 cv = c4p[c*(D/4) + d4];
      s = fmaf(tf[4*d4  ], cv.x, s);
      s = fmaf(tf[4*d4+1], cv.y, s);
      s = fmaf(tf[4*d4+2], cv.z, s);
      s = fmaf(tf[4*d4+3], cv.w, s);
    }
    if (s > best){ best = s; bc = c; }
  }
  // attn = (qb[src] + qkH[src] . tf) / 8   (L1-broadcast reads)
  float at = qb[src];
  const uint4* qr = (const uint4*)(qkH + (size_t)src * D);
  #pragma unroll
  for (int g = 0; g < 4; ++g){
    uint4 q4 = qr[g];
    at = fmaf(blo(q4.x), tf[16*g+ 0], at);
    at = fmaf(bhi(q4.x), tf[16*g+ 1], at);
    at = fmaf(blo(q4.y), tf[16*g+ 2], at);
    at = fmaf(bhi(q4.y), tf[16*g+ 3], at);
    at = fmaf(blo(q4.z), tf[16*g+ 4], at);
    at = fmaf(bhi(q4.z), tf[16*g+ 5], at);
    at = fmaf(blo(q4.w), tf[16*g+ 6], at);
    at = fmaf(bhi(q4.w), tf[16*g+ 7], at);
  }
  // NOTE: uint4 packs 8 bf16, so indexing is 8 per uint4 half... use 8/g:
  // (handled below with correct stride)
  at = qb[src];
  #pragma unroll
  for (int g = 0; g < 8; ++g){
    uint2 q2 = ((const uint2*)qr)[g];
    at = fmaf(blo(q2.x), tf[8*g+0], at);
    at = fmaf(bhi(q2.x), tf[8*g+1], at);
    at = fmaf(blo(q2.y), tf[8*g+2], at);
    at = fmaf(bhi(q2.y), tf[8*g+3], at);
    uint2 q2b = ((const uint2*)qr)[g];
    (void)q2b;
    unsigned w2 = ((const unsigned*)qr)[g*4+2];
    unsigned w3 = ((const unsigned*)qr)[g*4+3];
    (void)w2; (void)w3;
    break;
  }
  // clean correct version:
  {
    at = qb[src];
    const unsigned* qw = (const unsigned*)(qkH + (size_t)src * D);
    #pragma unroll
    for (int g = 0; g < 32; ++g){
      unsigned wp = qw[g];
      at = fmaf(blo(wp), tf[2*g  ], at);
      at = fmaf(bhi(wp), tf[2*g+1], at);
    }
  }
  at *= 0.125f;
  attnS[pos] = at;
  clS[pos] = (unsigned char)bc;
  atomicAdd(&s_epc[bc], 1u);
  __syncthreads();
  if (t < NC){
    unsigned v = s_epc[t];
    if (v) atomicAdd(&epc[t], v);
  }
}

// ---------------- P4: per-node softmax + T accumulation (wave per node) -----
#define EROW 20   // padded LDS row stride (floats) for ea staging
__global__ __launch_bounds__(256) void p4_node(
    const float* __restrict__ ea, const int2* __restrict__ pairS,
    const float* __restrict__ Wt, const float* __restrict__ bt,
    const float* __restrict__ attnS, const unsigned char* __restrict__ clS,
    const int* __restrict__ rowptr,
    float* __restrict__ T, float* __restrict__ S)
{
  __shared__ float s_den[4][NC];
  __shared__ int   s_cnt[4][NC];
  __shared__ float s_inv[4][NC];
  __shared__ float s_coef[4][64];
  __shared__ float s_ea[4][64][EROW];   // 20 KB
  int t = threadIdx.x, lane = t & 63, w = t >> 6;
  // Wt column for this lane in registers (lane-invariant across edges)
  float wl[ED];
  #pragma unroll
  for (int j = 0; j < ED; ++j) wl[j] = Wt[j*D + lane];
  float btl = bt[lane];
  if (lane < NC){ s_den[w][lane] = 0.0f; s_cnt[w][lane] = 0; }
  int node = blockIdx.x * 4 + w;
  int start = rowptr[node], end = rowptr[node + 1];
  // pass A: per-cluster denom + count (no max-shift; |attn| = O(1))
  for (int base = start; base < end; base += 64){
    int idx = base + lane;
    if (idx < end){
      float ex = __expf(attnS[idx]);
      int c = clS[idx];
      atomicAdd(&s_den[w][c], ex);
      atomicAdd(&s_cnt[w][c], 1);
    }
  }
  if (lane < NC){
    int   cc = s_cnt[w][lane];
    float dd = s_den[w][lane];
    s_inv[w][lane] = (cc > 0) ? 1.0f / (dd * (float)cc) : 0.0f;
    float sv = (cc > 0) ? 1.0f / (float)cc : 0.0f;   // softmax sums to 1
    sv += __shfl_xor(sv, 1); sv += __shfl_xor(sv, 2); sv += __shfl_xor(sv, 4);
    if (lane == 0) S[node] = sv;
  }
  // pass B: stage coef + ea rows per 64-edge chunk, then accumulate T
  float Tacc = 0.0f;
  for (int base = start; base < end; base += 64){
    int idx = base + lane;
    if (idx < end)
      s_coef[w][lane] = __expf(attnS[idx]) * s_inv[w][clS[idx]];
    // cooperative ea stage: 4 lanes per row (each lane one float4)
    #pragma unroll
    for (int r = 0; r < 4; ++r){
      int slot = base + r*16 + (lane >> 2);
      if (slot < end){
        int e = pairS[slot].x;
        float4 v = ((const float4*)ea)[(size_t)e*4 + (lane & 3)];
        *(float4*)&s_ea[w][slot - base][(lane & 3)*4] = v;
      }
    }
    int mm = min(64, end - base);
    for (int tt = 0; tt < mm; ++tt){
      float coef = s_coef[w][tt];               // uniform
      const float4* er = (const float4*)&s_ea[w][tt][0];
      float4 e0 = er[0], e1 = er[1], e2 = er[2], e3 = er[3];
      float tfv = btl;
      tfv = fmaf(e0.x, wl[0], tfv);  tfv = fmaf(e0.y, wl[1], tfv);
      tfv = fmaf(e0.z, wl[2], tfv);  tfv = fmaf(e0.w, wl[3], tfv);
      tfv = fmaf(e1.x, wl[4], tfv);  tfv = fmaf(e1.y, wl[5], tfv);
      tfv = fmaf(e1.z, wl[6], tfv);  tfv = fmaf(e1.w, wl[7], tfv);
      tfv = fmaf(e2.x, wl[8], tfv);  tfv = fmaf(e2.y, wl[9], tfv);
      tfv = fmaf(e2.z, wl[10], tfv); tfv = fmaf(e2.w, wl[11], tfv);
      tfv = fmaf(e3.x, wl[12], tfv); tfv = fmaf(e3.y, wl[13], tfv);
      tfv = fmaf(e3.z, wl[14], tfv); tfv = fmaf(e3.w, wl[15], tfv);
      tfv = fmaxf(tfv, 0.0f);
      Tacc = fmaf(coef, tfv, Tacc);
    }
  }
  T[(size_t)node * D + lane] = Tacc;
}

// ---------------- K5: fu = relu((T@Wvo + S*bvo)/nne + bo); out = x + fu@Wu+bu
__global__ __launch_bounds__(256) void k5_out(
    const float* __restrict__ x, const float* __restrict__ T, const float* __restrict__ S,
    const float* __restrict__ Wvo, const float* __restrict__ bvo,
    const unsigned* __restrict__ WuP, const float* __restrict__ bu,
    const float* __restrict__ bo, const unsigned* __restrict__ epc,
    float* __restrict__ out)
{
  __shared__ unsigned sWuP[8192];   // 32 KB packed bf16 Wu
  __shared__ float s_fu[16*64];     // 4 KB
  int t = threadIdx.x;
  #pragma unroll
  for (int i = 0; i < 8; ++i)
    ((uint4*)sWuP)[t + 256*i] = ((const uint4*)WuP)[t + 256*i];
  int lane = t & 63;
  int wg = __builtin_amdgcn_readfirstlane(t >> 6);
  int n0 = blockIdx.x * 16 + wg * 4;
  float nne = 0.0f;
  #pragma unroll
  for (int c = 0; c < NC; ++c) nne += (epc[c] > 0u) ? 1.0f : 0.0f;
  float inv = 1.0f / fmaxf(nne, 1.0f);
  float T0 = T[(size_t)(n0+0)*D + lane];
  float T1 = T[(size_t)(n0+1)*D + lane];
  float T2 = T[(size_t)(n0+2)*D + lane];
  float T3 = T[(size_t)(n0+3)*D + lane];
  float bvl = bvo[lane], bol = bo[lane];
  float f0 = S[n0+0]*bvl, f1 = S[n0+1]*bvl, f2 = S[n0+2]*bvl, f3 = S[n0+3]*bvl;
  #pragma unroll 8
  for (int i = 0; i < 64; ++i){
    float wv = Wvo[i*64 + lane];      // L1-resident (16 KB)
    f0 = fmaf(__shfl(T0, i), wv, f0);
    f1 = fmaf(__shfl(T1, i), wv, f1);
    f2 = fmaf(__shfl(T2, i), wv, f2);
    f3 = fmaf(__shfl(T3, i), wv, f3);
  }
  f0 = fmaxf(f0*inv + bol, 0.0f);
  f1 = fmaxf(f1*inv + bol, 0.0f);
  f2 = fmaxf(f2*inv + bol, 0.0f);
  f3 = fmaxf(f3*inv + bol, 0.0f);
  s_fu[(wg*4+0)*64 + lane] = f0;
  s_fu[(wg*4+1)*64 + lane] = f1;
  s_fu[(wg*4+2)*64 + lane] = f2;
  s_fu[(wg*4+3)*64 + lane] = f3;
  __syncthreads();
  float4 bu4 = ((const float4*)bu)[lane];
  float4 o0 = ((const float4*)(x + (size_t)(n0+0)*INCH))[lane];
  float4 o1 = ((const float4*)(x + (size_t)(n0+1)*INCH))[lane];
  float4 o2 = ((const float4*)(x + (size_t)(n0+2)*INCH))[lane];
  float4 o3 = ((const float4*)(x + (size_t)(n0+3)*INCH))[lane];
  o0.x += bu4.x; o0.y += bu4.y; o0.z += bu4.z; o0.w += bu4.w;
  o1.x += bu4.x; o1.y += bu4.y; o1.z += bu4.z; o1.w += bu4.w;
  o2.x += bu4.x; o2.y += bu4.y; o2.z += bu4.z; o2.w += bu4.w;
  o3.x += bu4.x; o3.y += bu4.y; o3.z += bu4.z; o3.w += bu4.w;
  const float2* fu2 = (const float2*)s_fu;
  #pragma unroll 4
  for (int d2 = 0; d2 < 32; ++d2){
    uint4 wp = *(const uint4*)&sWuP[d2*256 + lane*4];
    float4 wlv = { blo(wp.x), blo(wp.y), blo(wp.z), blo(wp.w) };
    float4 wh  = { bhi(wp.x), bhi(wp.y), bhi(wp.z), bhi(wp.w) };
    float2 g0 = fu2[(wg*4+0)*32 + d2];
    float2 g1 = fu2[(wg*4+1)*32 + d2];
    float2 g2 = fu2[(wg*4+2)*32 + d2];
    float2 g3 = fu2[(wg*4+3)*32 + d2];
    o0.x = fmaf(g0.x, wlv.x, o0.x); o0.y = fmaf(g0.x, wlv.y, o0.y);
    o0.z = fmaf(g0.x, wlv.z, o0.z); o0.w = fmaf(g0.x, wlv.w, o0.w);
    o0.x = fmaf(g0.y, wh.x, o0.x);  o0.y = fmaf(g0.y, wh.y, o0.y);
    o0.z = fmaf(g0.y, wh.z, o0.z);  o0.w = fmaf(g0.y, wh.w, o0.w);
    o1.x = fmaf(g1.x, wlv.x, o1.x); o1.y = fmaf(g1.x, wlv.y, o1.y);
    o1.z = fmaf(g1.x, wlv.z, o1.z); o1.w = fmaf(g1.x, wlv.w, o1.w);
    o1.x = fmaf(g1.y, wh.x, o1.x);  o1.y = fmaf(g1.y, wh.y, o1.y);
    o1.z = fmaf(g1.y, wh.z, o1.z);  o1.w = fmaf(g1.y, wh.w, o1.w);
    o2.x = fmaf(g2.x, wlv.x, o2.x); o2.y = fmaf(g2.x, wlv.y, o2.y);
    o2.z = fmaf(g2.x, wlv.z, o2.z); o2.w = fmaf(g2.x, wlv.w, o2.w);
    o2.x = fmaf(g2.y, wh.x, o2.x);  o2.y = fmaf(g2.y, wh.y, o2.y);
    o2.z = fmaf(g2.y, wh.z, o2.z);  o2.w = fmaf(g2.y, wh.w, o2.w);
    o3.x = fmaf(g3.x, wlv.x, o3.x); o3.y = fmaf(g3.x, wlv.y, o3.y);
    o3.z = fmaf(g3.x, wlv.z, o3.z); o3.w = fmaf(g3.x, wlv.w, o3.w);
    o3.x = fmaf(g3.y, wh.x, o3.x);  o3.y = fmaf(g3.y, wh.y, o3.y);
    o3.z = fmaf(g3.y, wh.z, o3.z);  o3.w = fmaf(g3.y, wh.w, o3.w);
  }
  ((float4*)(out + (size_t)(n0+0)*INCH))[lane] = o0;
  ((float4*)(out + (size_t)(n0+1)*INCH))[lane] = o1;
  ((float4*)(out + (size_t)(n0+2)*INCH))[lane] = o2;
  ((float4*)(out + (size_t)(n0+3)*INCH))[lane] = o3;
}

extern "C" void kernel_launch(void* const* d_in, const int* in_sizes, int n_in,
                              void* d_out, int out_size, void* d_ws, size_t ws_size,
                              hipStream_t stream)
{
  const float* x  = (const float*)d_in[0];
  const float* ea = (const float*)d_in[1];
  const int* eidx = (const int*)d_in[2];      // [2,E]; row 0 = src
  const float* Wd = (const float*)d_in[3];  const float* bd = (const float*)d_in[4];
  const float* Wu = (const float*)d_in[5];  const float* bu = (const float*)d_in[6];
  const float* Wt = (const float*)d_in[7];  const float* bt = (const float*)d_in[8];
  const float* Wq = (const float*)d_in[9];  const float* bq = (const float*)d_in[10];
  const float* Wk = (const float*)d_in[11]; const float* bk = (const float*)d_in[12];
  const float* Wv = (const float*)d_in[13]; const float* bv = (const float*)d_in[14];
  const float* ce = (const float*)d_in[15];
  const float* Wo = (const float*)d_in[16]; const float* bo = (const float*)d_in[17];
  float* out = (float*)d_out;

  size_t need = 0;
  need += (size_t)NN*4;          // cnt
  need += (size_t)NN*4;          // fill
  need += 64;                    // epc
  size_t zbytes = need;          // zero region
  need += (size_t)(NN+4)*4;      // rowptr
  need += 1024;                  // bsum
  need += (size_t)NN*D*2;        // qkH (bf16)
  need += (size_t)NN*4;          // qb
  need += (size_t)EE*8;          // pairS
  need += (size_t)EE*4;          // attnS
  need += (size_t)EE;            // clS
  need += (size_t)NN*D*4;        // T
  need += (size_t)NN*4;          // S
  need += 4096*4 + 256 + 256 + 16 + 4096*4 + 256;  // M,cvec,u,s0,Wvo,bvo
  need += 8192*4 + 8192*4;       // WdP, WuP

  char* w = (char*)d_ws;
  if (ws_size < need){
    void* p = nullptr;
    hipGetSymbolAddress(&p, HIP_SYMBOL(g_ws));
    w = (char*)p;
  }
  size_t off = 0;
  int*      cnt    = (int*)(w + off);      off += (size_t)NN*4;
  int*      fill   = (int*)(w + off);      off += (size_t)NN*4;
  unsigned* epc    = (unsigned*)(w + off); off += 64;
  int*      rowptr = (int*)(w + off);      off += (size_t)(NN+4)*4;
  int*      bsum   = (int*)(w + off);      off += 1024;
  unsigned short* qkH = (unsigned short*)(w + off); off += (size_t)NN*D*2;
  float*    qb     = (float*)(w + off);    off += (size_t)NN*4;
  int2*     pairS  = (int2*)(w + off);     off += (size_t)EE*8;
  float*    attnS  = (float*)(w + off);    off += (size_t)EE*4;
  unsigned char* clS = (unsigned char*)(w + off); off += (size_t)EE;
  off = (off + 15) & ~(size_t)15;
  float*    T      = (float*)(w + off);    off += (size_t)NN*D*4;
  float*    S      = (float*)(w + off);    off += (size_t)NN*4;
  float*    M      = (float*)(w + off);    off += 4096*4;
  float*    cvec   = (float*)(w + off);    off += 256;
  float*    u      = (float*)(w + off);    off += 256;
  float*    s0     = (float*)(w + off);    off += 16;
  float*    Wvo    = (float*)(w + off);    off += 4096*4;
  float*    bvo    = (float*)(w + off);    off += 256;
  unsigned* WdP    = (unsigned*)(w + off); off += 8192*4;
  unsigned* WuP    = (unsigned*)(w + off); off += 8192*4;

  int zwords = (int)(zbytes / 4);
  Adapter_30872224923942_kernel<<<dim3(128), dim3(256), 0, stream>>>((unsigned*)w, zwords);
  kpre<<<dim3(41), dim3(256), 0, stream>>>(Wq, bq, Wk, bk, Wv, bv, Wo, Wd, Wu,
                                           M, cvec, u, s0, Wvo, bvo, WdP, WuP);
  p1_hist<<<dim3(EE/256), dim3(256), 0, stream>>>(eidx, cnt);
  s1_scan<<<dim3(NB), dim3(256), 0, stream>>>(cnt, rowptr, bsum);
  s2_scan<<<dim3(1),  dim3(256), 0, stream>>>(bsum);
  s3_add <<<dim3(NB), dim3(256), 0, stream>>>(rowptr, bsum);
  p2_build<<<dim3(EE/256), dim3(256), 0, stream>>>(eidx, rowptr, fill, pairS);
  k1_node<<<dim3(NN/16), dim3(256), 0, stream>>>(x, WdP, bd, M, cvec, u, s0, qkH, qb);
  p3_edge<<<dim3(EE/256), dim3(256), 0, stream>>>(ea, pairS, Wt, bt, ce, qkH, qb,
                                                  attnS, clS, epc);
  p4_node<<<dim3(NN/4), dim3(256), 0, stream>>>(ea, pairS, Wt, bt, attnS, clS, rowptr, T, S);
  k5_out <<<dim3(NN/16), dim3(256), 0, stream>>>(x, T, S, Wvo, bvo, WuP, bu, bo, epc, out);
}